// Round 9
// baseline (144.482 us; speedup 1.0000x reference)
//
#include <hip/hip_runtime.h>
#include <hip/hip_fp16.h>

// DSA varlen sparse attention, MI355X — round 9.
// R8 post-mortem: fp8 failed numerics (0.234 > 0.083) -> fp16 is the byte floor.
// Cross-round: line rate ∝ occupancy (R2 0.63/cyc @85%, R7 0.50 @62%) ->
// latency/outstanding bound, not a throughput wall. Fix: TWO tokens per wave
// (t, t+4; same doc+head => same base ptrs, one seg lookup), streams
// interleaved in the rg-loop so each wave keeps ~2x loads in flight even
// after the compiler sinks loads to uses. Blocks 16384 -> 8192.
// Numerics identical to R7 (absmax 0.0156 expected).

#define T_TOK 4096
#define NH    16
#define HD    64
#define KSEL  64
#define KV_ELEMS (T_TOK * NH * HD)     // 4194304 per tensor

typedef _Float16 h2v __attribute__((ext_vector_type(2)));

static __device__ __forceinline__ h2v u2h2v(unsigned u) {
    return __builtin_bit_cast(h2v, u);
}
static __device__ __forceinline__ __half2 u2h2(unsigned u) {
    return __builtin_bit_cast(__half2, u);
}
static __device__ __forceinline__ h2v f2h2v(float a, float b) {
    __half2 t = __floats2half2_rn(a, b);   // v_cvt_pkrtz_f16_f32
    return __builtin_bit_cast(h2v, t);
}

// Cross-lane adds (R7-proven).
// 0xB1=quad_perm xor1  0x4E=quad_perm xor2  0x141=row_half_mirror (xor4 on
// quad-uniform)  0x140=row_mirror (xor8 on 8-group-uniform)
template<int CTRL>
static __device__ __forceinline__ float dpp_addf(float x) {
    const int s = __builtin_amdgcn_update_dpp(
        0, __builtin_bit_cast(int, x), CTRL, 0xF, 0xF, true);
    return x + __builtin_bit_cast(float, s);
}
template<int IMM>
static __device__ __forceinline__ float swz_addf(float x) {
    const int s = __builtin_amdgcn_ds_swizzle(__builtin_bit_cast(int, x), IMM);
    return x + __builtin_bit_cast(float, s);
}
template<int IMM>
static __device__ __forceinline__ __half2 swz_hadd2(__half2 x) {
    const int s = __builtin_amdgcn_ds_swizzle(__builtin_bit_cast(int, x), IMM);
    return __hadd2(x, __builtin_bit_cast(__half2, s));
}
static __device__ __forceinline__ __half2 sh32_hadd2(__half2 x) {
    const int s = __shfl_xor(__builtin_bit_cast(int, x), 32, 64);
    return __hadd2(x, __builtin_bit_cast(__half2, s));
}

// ---------------- fp32 -> fp16 conversion pre-pass ----------------
__global__ __launch_bounds__(256) void cvt_fp16(
    const float4* __restrict__ kM, const float4* __restrict__ vM,
    uint2* __restrict__ kH, uint2* __restrict__ vH)
{
    const int n4 = KV_ELEMS / 4;
    const int i  = blockIdx.x * blockDim.x + threadIdx.x;
    const bool isK = i < n4;
    const float4 f = isK ? kM[i] : vM[i - n4];
    __half2 lo = __floats2half2_rn(f.x, f.y);
    __half2 hi = __floats2half2_rn(f.z, f.w);
    uint2 u;
    u.x = __builtin_bit_cast(unsigned, lo);
    u.y = __builtin_bit_cast(unsigned, hi);
    if (isK) kH[i] = u; else vH[i - n4] = u;
}

// ---------------- main kernel: 2 tokens per wave ----------------
__global__ __launch_bounds__(256) void dsa_sparse_attn(
    const float*  __restrict__ qM,
    const __half* __restrict__ kH,
    const __half* __restrict__ vH,
    const int*    __restrict__ cu,
    const int*    __restrict__ tidx,
    const float*  __restrict__ tsc,
    float*        __restrict__ out,
    int num_docs)
{
    const int wave = threadIdx.x >> 6;
    const int lane = threadIdx.x & 63;

    // XCD-aware (doc,head)-slice swizzle; 8192 blocks, 2 tokens/wave.
    const int b            = blockIdx.x;
    const int xcd          = b & 7;
    const int j            = b >> 3;            // 0..1023
    const int token_block  = j & 127;           // 0..127
    const int slice_within = j >> 7;            // 0..7
    const int s            = xcd + (slice_within << 3);   // 0..63
    const int h            = s & (NH - 1);
    const int doc          = s >> 4;            // 0..3 (1024 tokens each)
    const int tA           = doc * (T_TOK / 4) + token_block * 8 + wave;
    const int tB           = tA + 4;
    const int gidA         = tA * NH + h;
    const int gidB         = tB * NH + h;

    // --- doc segment (wave-uniform; same doc for both tokens) ---
    int seg = 0;
    for (int i = 1; i < num_docs; ++i)
        if (tA >= cu[i]) seg = i;
    const int start = cu[seg];
    const int len   = cu[seg + 1] - start;

    // --- per-lane gather indices (k = lane), clamped ---
    int iA = tidx[tA * KSEL + lane] - start;
    iA = iA < 0 ? 0 : (iA > len - 1 ? len - 1 : iA);
    const int gA = start + iA;
    int iB = tidx[tB * KSEL + lane] - start;
    iB = iB < 0 ? 0 : (iB > len - 1 ? len - 1 : iB);
    const int gB = start + iB;

    const int laneQ8 = lane >> 3;   // row slot within each group of 8 rows
    const int laneC8 = lane & 7;    // uint4 (16B) chunk within the 128B row

    // --- q -> fp16 chunks (dims [laneC8*8,+8)) for both streams ---
    const float4* qvA = (const float4*)(qM + gidA * HD);
    const float4 aA0 = qvA[laneC8 * 2];
    const float4 aA1 = qvA[laneC8 * 2 + 1];
    const h2v qA0 = f2h2v(aA0.x, aA0.y), qA1 = f2h2v(aA0.z, aA0.w);
    const h2v qA2 = f2h2v(aA1.x, aA1.y), qA3 = f2h2v(aA1.z, aA1.w);
    const float4* qvB = (const float4*)(qM + gidB * HD);
    const float4 aB0 = qvB[laneC8 * 2];
    const float4 aB1 = qvB[laneC8 * 2 + 1];
    const h2v qB0 = f2h2v(aB0.x, aB0.y), qB1 = f2h2v(aB0.z, aB0.w);
    const h2v qB2 = f2h2v(aB1.x, aB1.y), qB3 = f2h2v(aB1.z, aB1.w);

    const uint4* kf = (const uint4*)kH;   // fp16 row = 8 uint4 (128B)
    const uint4* vf = (const uint4*)vH;
    const float* scbA = tsc + tA * KSEL;
    const float* scbB = tsc + tB * KSEL;

    float S2A = 0.f, S2B = 0.f;
    __half2 accA0 = u2h2(0u), accA1 = u2h2(0u), accA2 = u2h2(0u), accA3 = u2h2(0u);
    __half2 accB0 = u2h2(0u), accB1 = u2h2(0u), accB2 = u2h2(0u), accB3 = u2h2(0u);

    #pragma unroll
    for (int rg = 0; rg < 8; ++rg) {
        const int row = rg * 8 + laneQ8;
        const int grA = __shfl(gA, row, 64);
        const int grB = __shfl(gB, row, 64);
        const int baseA = (grA * NH + h) * 8 + laneC8;
        const int baseB = (grB * NH + h) * 8 + laneC8;
        // 4 independent 16B loads issued together (2 streams x K,V)
        const uint4 kkA = kf[baseA];
        const uint4 vvA = vf[baseA];
        const uint4 kkB = kf[baseB];
        const uint4 vvB = vf[baseB];
        const float scA = scbA[row];
        const float scB = scbB[row];

        // stream A: partial dot, DPP row-reduce, weight, fma
        float pA = 0.f;
        pA = __builtin_amdgcn_fdot2(u2h2v(kkA.x), qA0, pA, false);
        pA = __builtin_amdgcn_fdot2(u2h2v(kkA.y), qA1, pA, false);
        pA = __builtin_amdgcn_fdot2(u2h2v(kkA.z), qA2, pA, false);
        pA = __builtin_amdgcn_fdot2(u2h2v(kkA.w), qA3, pA, false);
        // stream B interleaved
        float pB = 0.f;
        pB = __builtin_amdgcn_fdot2(u2h2v(kkB.x), qB0, pB, false);
        pB = __builtin_amdgcn_fdot2(u2h2v(kkB.y), qB1, pB, false);
        pB = __builtin_amdgcn_fdot2(u2h2v(kkB.z), qB2, pB, false);
        pB = __builtin_amdgcn_fdot2(u2h2v(kkB.w), qB3, pB, false);

        pA = dpp_addf<0xB1>(pA);  pB = dpp_addf<0xB1>(pB);   // xor1
        pA = dpp_addf<0x4E>(pA);  pB = dpp_addf<0x4E>(pB);   // xor2
        pA = dpp_addf<0x141>(pA); pB = dpp_addf<0x141>(pB);  // xor4

        const float wA = __expf(pA * 0.125f) * scA;   // D^-0.5 = 1/8
        const float wB = __expf(pB * 0.125f) * scB;
        S2A += wA;  S2B += wB;
        const __half2 wA2 = __floats2half2_rn(wA, wA);
        const __half2 wB2 = __floats2half2_rn(wB, wB);
        accA0 = __hfma2(wA2, u2h2(vvA.x), accA0);
        accA1 = __hfma2(wA2, u2h2(vvA.y), accA1);
        accA2 = __hfma2(wA2, u2h2(vvA.z), accA2);
        accA3 = __hfma2(wA2, u2h2(vvA.w), accA3);
        accB0 = __hfma2(wB2, u2h2(vvB.x), accB0);
        accB1 = __hfma2(wB2, u2h2(vvB.y), accB1);
        accB2 = __hfma2(wB2, u2h2(vvB.z), accB2);
        accB3 = __hfma2(wB2, u2h2(vvB.w), accB3);
    }

    // ---- S2 = sum over row-slots (uniform within 8-lane groups) ----
    S2A = dpp_addf<0x140>(S2A);       S2B = dpp_addf<0x140>(S2B);   // xor8
    S2A = swz_addf<0x401F>(S2A);      S2B = swz_addf<0x401F>(S2B);  // xor16
    S2A += __shfl_xor(S2A, 32, 64);   S2B += __shfl_xor(S2B, 32, 64);

    // ---- reduce acc across row-slots (lane bits 3,4,5) ----
    accA0 = swz_hadd2<0x201F>(accA0); accA1 = swz_hadd2<0x201F>(accA1);
    accA2 = swz_hadd2<0x201F>(accA2); accA3 = swz_hadd2<0x201F>(accA3);
    accB0 = swz_hadd2<0x201F>(accB0); accB1 = swz_hadd2<0x201F>(accB1);
    accB2 = swz_hadd2<0x201F>(accB2); accB3 = swz_hadd2<0x201F>(accB3);
    accA0 = swz_hadd2<0x401F>(accA0); accA1 = swz_hadd2<0x401F>(accA1);
    accA2 = swz_hadd2<0x401F>(accA2); accA3 = swz_hadd2<0x401F>(accA3);
    accB0 = swz_hadd2<0x401F>(accB0); accB1 = swz_hadd2<0x401F>(accB1);
    accB2 = swz_hadd2<0x401F>(accB2); accB3 = swz_hadd2<0x401F>(accB3);
    accA0 = sh32_hadd2(accA0); accA1 = sh32_hadd2(accA1);
    accA2 = sh32_hadd2(accA2); accA3 = sh32_hadd2(accA3);
    accB0 = sh32_hadd2(accB0); accB1 = sh32_hadd2(accB1);
    accB2 = sh32_hadd2(accB2); accB3 = sh32_hadd2(accB3);

    if (laneQ8 == 0) {
        const float invA = __builtin_amdgcn_rcpf(S2A);
        const float2 a0 = __half22float2(accA0);
        const float2 a1 = __half22float2(accA1);
        const float2 a2 = __half22float2(accA2);
        const float2 a3 = __half22float2(accA3);
        float4* opA = (float4*)(out + gidA * HD + laneC8 * 8);
        opA[0] = make_float4(a0.x * invA, a0.y * invA, a1.x * invA, a1.y * invA);
        opA[1] = make_float4(a2.x * invA, a2.y * invA, a3.x * invA, a3.y * invA);
        const float invB = __builtin_amdgcn_rcpf(S2B);
        const float2 b0 = __half22float2(accB0);
        const float2 b1 = __half22float2(accB1);
        const float2 b2 = __half22float2(accB2);
        const float2 b3 = __half22float2(accB3);
        float4* opB = (float4*)(out + gidB * HD + laneC8 * 8);
        opB[0] = make_float4(b0.x * invB, b0.y * invB, b1.x * invB, b1.y * invB);
        opB[1] = make_float4(b2.x * invB, b2.y * invB, b3.x * invB, b3.y * invB);
    }
}

extern "C" void kernel_launch(void* const* d_in, const int* in_sizes, int n_in,
                              void* d_out, int out_size, void* d_ws, size_t ws_size,
                              hipStream_t stream) {
    const float* q   = (const float*)d_in[0];
    const float* k   = (const float*)d_in[1];
    const float* v   = (const float*)d_in[2];
    const int*   cu  = (const int*)d_in[3];
    const int*   ti  = (const int*)d_in[4];
    const float* ts  = (const float*)d_in[5];
    float*       out = (float*)d_out;
    const int num_docs = in_sizes[3] - 1;

    __half* kH = (__half*)d_ws;
    __half* vH = kH + KV_ELEMS;

    const int n4 = KV_ELEMS / 4;
    hipLaunchKernelGGL(cvt_fp16, dim3(2 * n4 / 256), dim3(256), 0, stream,
                       (const float4*)k, (const float4*)v,
                       (uint2*)kH, (uint2*)vH);

    // 2 tokens per wave -> 32768 waves -> 8192 blocks
    hipLaunchKernelGGL(dsa_sparse_attn, dim3(8192), dim3(256), 0,
                       stream, q, (const __half*)kH, (const __half*)vH,
                       cu, ti, ts, out, num_docs);
}

// Round 10
// 141.866 us; speedup vs baseline: 1.0184x; 1.0184x over previous
//
#include <hip/hip_runtime.h>
#include <hip/hip_fp16.h>

// DSA varlen sparse attention, MI355X — round 10.
// R9 post-mortem: line rate pinned at ~0.5 lines/cyc/CU across 4 structures
// and 2x per-wave ILP -> throughput ceiling on SCATTERED line requests
// (sequential L2 µbench = ~0.94 lines/cyc). Test contiguity at constant bytes:
//   wave = token x 4 heads (topk indices are head-shared). Per k-row, ONE
//   dwordx4 instruction covers a fully CONTIGUOUS 1KB region: K+V interleaved
//   per (row,head) at 8B granularity (lane l = head(l>>4), chunk(l&15) gets
//   4 K-halfs + 4 V-halfs in one 16B load).
//   g routing via __shfl(g, literal) -> v_readlane (no LDS pipe). Dot reduced
//   in 16-lane groups via pure DPP. NO cross-lane acc reduction (each lane
//   owns its out dims). q pre-scaled by 0.125. sc via scalar loads.
// Same numerics as R7/R9 (absmax 0.0156 expected).

#define T_TOK 4096
#define NH    16
#define HD    64
#define KSEL  64
#define ROWS  (T_TOK * NH)             // 65536 row-heads

typedef _Float16 h2v __attribute__((ext_vector_type(2)));

static __device__ __forceinline__ h2v u2h2v(unsigned u) {
    return __builtin_bit_cast(h2v, u);
}
static __device__ __forceinline__ __half2 u2h2(unsigned u) {
    return __builtin_bit_cast(__half2, u);
}
static __device__ __forceinline__ h2v f2h2v(float a, float b) {
    __half2 t = __floats2half2_rn(a, b);   // v_cvt_pkrtz_f16_f32
    return __builtin_bit_cast(h2v, t);
}
// DPP adds: 0xB1=xor1  0x4E=xor2  0x141=row_half_mirror(xor4 on quad-uniform)
// 0x140=row_mirror(xor8 on 8-uniform) — all within 16-lane DPP rows.
template<int CTRL>
static __device__ __forceinline__ float dpp_addf(float x) {
    const int s = __builtin_amdgcn_update_dpp(
        0, __builtin_bit_cast(int, x), CTRL, 0xF, 0xF, true);
    return x + __builtin_bit_cast(float, s);
}

// ---- cvt pre-pass: fp32 K,V -> interleaved fp16 KV.
// Layout: row-head rh, chunk c (0..15): uint4 = {K[rh,4c..4c+3], V[rh,4c..4c+3]}
// each as 4 fp16. One row-head = 16 uint4 = 256B; 4-head group = 1KB contig.
__global__ __launch_bounds__(256) void cvt_kv(
    const float* __restrict__ kM, const float* __restrict__ vM,
    uint4* __restrict__ kvH)
{
    const int i  = blockIdx.x * blockDim.x + threadIdx.x;   // ROWS*16 threads
    const int rh = i >> 4;
    const int c  = i & 15;
    const float4 fk = *(const float4*)(kM + rh * HD + c * 4);
    const float4 fv = *(const float4*)(vM + rh * HD + c * 4);
    uint4 o;
    o.x = __builtin_bit_cast(unsigned, __floats2half2_rn(fk.x, fk.y));
    o.y = __builtin_bit_cast(unsigned, __floats2half2_rn(fk.z, fk.w));
    o.z = __builtin_bit_cast(unsigned, __floats2half2_rn(fv.x, fv.y));
    o.w = __builtin_bit_cast(unsigned, __floats2half2_rn(fv.z, fv.w));
    kvH[i] = o;
}

// ---------------- main kernel: 1 token x 4 heads per wave ----------------
__global__ __launch_bounds__(256) void dsa_sparse_attn(
    const float* __restrict__ qM,
    const uint4* __restrict__ kvH,
    const int*   __restrict__ cu,
    const int*   __restrict__ tidx,
    const float* __restrict__ tsc,
    float*       __restrict__ out,
    int num_docs)
{
    const int wave = threadIdx.x >> 6;
    const int lane = threadIdx.x & 63;

    // 4096 blocks. slice = (doc, head-group): 16 slices, 2 per XCD.
    // Slice working set (fp16 K+V, 4 heads, 1024 rows) = 1 MB << 4 MiB L2.
    const int b     = blockIdx.x;
    const int xcd   = b & 7;
    const int j     = b >> 3;           // 0..511
    const int tb    = j & 255;          // token block within slice
    const int sw    = j >> 8;           // 0..1
    const int slice = xcd + (sw << 3);  // 0..15
    const int hg    = slice & 3;
    const int doc   = slice >> 2;
    const int h0    = hg << 2;
    const int t     = doc * (T_TOK / 4) + tb * 4 + wave;

    // --- doc segment (wave-uniform; swizzle's doc notion is only a t-map,
    // correctness comes from this cu lookup) ---
    int seg = 0;
    for (int i = 1; i < num_docs; ++i)
        if (t >= cu[i]) seg = i;
    const int start = cu[seg];
    const int len   = cu[seg + 1] - start;

    // --- per-lane gather index (k = lane), clamped ---
    int loc = tidx[t * KSEL + lane] - start;
    loc = loc < 0 ? 0 : (loc > len - 1 ? len - 1 : loc);
    const int g = start + loc;            // selected row for k = lane

    const int lh = lane >> 4;    // head within group (0..3)
    const int ld = lane & 15;    // dim chunk (4 dims each)

    // --- q chunk, pre-scaled by D^-0.5 = 0.125, converted fp16 ---
    const float4 qf = *(const float4*)(qM + (t * NH + h0 + lh) * HD + ld * 4);
    const h2v q01 = f2h2v(qf.x * 0.125f, qf.y * 0.125f);
    const h2v q23 = f2h2v(qf.z * 0.125f, qf.w * 0.125f);

    const float* scb = tsc + t * KSEL;

    float S2 = 0.f;
    __half2 acc0 = u2h2(0u), acc1 = u2h2(0u);

    #pragma unroll
    for (int r = 0; r < KSEL; ++r) {
        const int gr = __shfl(g, r, 64);            // literal lane -> readlane
        // ONE dwordx4: 64 lanes cover 1KB contiguous (4 heads' K+V of row gr)
        const uint4 kv = kvH[((gr * NH + h0) << 4) + lane];
        // score partial: this lane's 4 dims of head h0+lh
        float p = 0.f;
        p = __builtin_amdgcn_fdot2(u2h2v(kv.x), q01, p, false);
        p = __builtin_amdgcn_fdot2(u2h2v(kv.y), q23, p, false);
        // reduce across the 16 lanes of this head group (pure DPP/VALU)
        p = dpp_addf<0xB1>(p);      // xor1
        p = dpp_addf<0x4E>(p);      // xor2
        p = dpp_addf<0x141>(p);     // xor4
        p = dpp_addf<0x140>(p);     // xor8
        // unnormalized weight (q pre-scaled; |score|<~6 so exp safe)
        const float w = __expf(p) * scb[r];          // scb[r]: scalar load
        S2 += w;
        const __half2 w2 = __floats2half2_rn(w, w);
        acc0 = __hfma2(w2, u2h2(kv.z), acc0);        // V dims 4ld..4ld+1
        acc1 = __hfma2(w2, u2h2(kv.w), acc1);        // V dims 4ld+2..4ld+3
    }

    // Each lane owns out[t, h0+lh, 4ld..4ld+3] — no cross-lane reduction.
    const float inv = __builtin_amdgcn_rcpf(S2);
    const float2 a0 = __half22float2(acc0);
    const float2 a1 = __half22float2(acc1);
    *(float4*)(out + (t * NH + h0 + lh) * HD + ld * 4) =
        make_float4(a0.x * inv, a0.y * inv, a1.x * inv, a1.y * inv);
}

extern "C" void kernel_launch(void* const* d_in, const int* in_sizes, int n_in,
                              void* d_out, int out_size, void* d_ws, size_t ws_size,
                              hipStream_t stream) {
    const float* q   = (const float*)d_in[0];
    const float* k   = (const float*)d_in[1];
    const float* v   = (const float*)d_in[2];
    const int*   cu  = (const int*)d_in[3];
    const int*   ti  = (const int*)d_in[4];
    const float* ts  = (const float*)d_in[5];
    float*       out = (float*)d_out;
    const int num_docs = in_sizes[3] - 1;

    uint4* kvH = (uint4*)d_ws;    // ROWS * 256B = 16.8 MB

    hipLaunchKernelGGL(cvt_kv, dim3(ROWS * 16 / 256), dim3(256), 0, stream,
                       k, v, kvH);

    // 1 token x 4 heads per wave -> 16384 waves -> 4096 blocks
    hipLaunchKernelGGL(dsa_sparse_attn, dim3(4096), dim3(256), 0, stream,
                       q, kvH, cu, ti, ts, out, num_docs);
}